// Round 5
// baseline (368.962 us; speedup 1.0000x reference)
//
#include <hip/hip_runtime.h>
#include <math.h>

#define NN 100000
#define EE 640000
#define INCH 256
#define HIDC 128
#define OUTC 64
#define NCHUNK ((NN + 255) / 256)   // 391 scan chunks

typedef __attribute__((ext_vector_type(8))) short short8;
typedef __attribute__((ext_vector_type(8))) unsigned short ushort8;
typedef __attribute__((ext_vector_type(4))) float floatx4;

__device__ __forceinline__ short f2bf(float f) {
    unsigned u = __float_as_uint(f);
    u += 0x7fff + ((u >> 16) & 1);   // round-to-nearest-even
    return (short)(u >> 16);
}

__device__ __forceinline__ float bf2f(unsigned short u) {
    return __uint_as_float(((unsigned)u) << 16);
}

// packed f32x2 -> bf16x2 (RNE), one VALU op instead of ~8
__device__ __forceinline__ unsigned pk2bf(float lo, float hi) {
    unsigned r;
    asm("v_cvt_pk_bf16_f32 %0, %1, %2" : "=v"(r) : "v"(lo), "v"(hi));
    return r;
}

// async global->LDS DMA, 16B per lane; LDS dest = wave-uniform base + lane*16
__device__ __forceinline__ void async_copy16(const void* g, void* l) {
    __builtin_amdgcn_global_load_lds(
        (const __attribute__((address_space(1))) unsigned int*)g,
        (__attribute__((address_space(3))) unsigned int*)l,
        16, 0, 0);
}

// ---------------- degree ----------------
__global__ void k_deg_zero(int* __restrict__ deg) {
    int i = blockIdx.x * 256 + threadIdx.x;
    if (i < NN) deg[i] = 0;
}

__global__ void k_deg_count(const int* __restrict__ dstp, int* __restrict__ deg) {
    int e = blockIdx.x * 256 + threadIdx.x;
    if (e < EE) atomicAdd(&deg[dstp[e]], 1);
}

// ---------------- scan (exclusive prefix over deg) ----------------
__global__ __launch_bounds__(256) void k_scan1(const int* __restrict__ deg,
                                               int* __restrict__ partials) {
    int i = blockIdx.x * 256 + threadIdx.x;
    int v = (i < NN) ? deg[i] : 0;
    for (int o = 32; o; o >>= 1) v += __shfl_down(v, o, 64);
    __shared__ int sm[4];
    if ((threadIdx.x & 63) == 0) sm[threadIdx.x >> 6] = v;
    __syncthreads();
    if (threadIdx.x == 0) partials[blockIdx.x] = sm[0] + sm[1] + sm[2] + sm[3];
}

__global__ __launch_bounds__(512) void k_scan2(int* __restrict__ partials) {
    __shared__ int sm[512];
    int t = threadIdx.x;
    int v = (t < NCHUNK) ? partials[t] : 0;
    sm[t] = v;
    __syncthreads();
    for (int o = 1; o < 512; o <<= 1) {
        int add = (t >= o) ? sm[t - o] : 0;
        __syncthreads();
        sm[t] += add;
        __syncthreads();
    }
    if (t < NCHUNK) partials[t] = sm[t] - v;  // exclusive
}

__global__ __launch_bounds__(256) void k_scan3(const int* __restrict__ deg,
                                               const int* __restrict__ partials,
                                               int* __restrict__ row_off,
                                               int* __restrict__ cursor,
                                               float* __restrict__ dinv) {
    int t = threadIdx.x;
    int i = blockIdx.x * 256 + t;
    int v = (i < NN) ? deg[i] : 0;
    __shared__ int sm[256];
    sm[t] = v;
    __syncthreads();
    for (int o = 1; o < 256; o <<= 1) {
        int add = (t >= o) ? sm[t - o] : 0;
        __syncthreads();
        sm[t] += add;
        __syncthreads();
    }
    if (i < NN) {
        int excl = partials[blockIdx.x] + sm[t] - v;
        row_off[i] = excl;
        cursor[i] = excl;
        dinv[i] = rsqrtf((float)(v + 1));  // +1 self-loop
    }
}

// ---------------- CSR fill ----------------
__global__ void k_fill(const int* __restrict__ srcp, const int* __restrict__ dstp,
                       int* __restrict__ cursor, int* __restrict__ esrc) {
    int e = blockIdx.x * 256 + threadIdx.x;
    if (e < EE) {
        int d = dstp[e];
        int pos = atomicAdd(&cursor[d], 1);
        esrc[pos] = srcp[e];
    }
}

// ---------------- weight prep: transpose + bf16 ----------------
__global__ void k_prep(const float* __restrict__ W1,
                       const float* __restrict__ Wmu, const float* __restrict__ bmu,
                       const float* __restrict__ Wls, const float* __restrict__ bls,
                       short* __restrict__ wt, short* __restrict__ wct,
                       float* __restrict__ bcat) {
    int i = blockIdx.x * 256 + threadIdx.x;
    if (i < 32768) {
        int n = i >> 8, k = i & 255;
        wt[i] = f2bf(W1[k * HIDC + n]);
    } else if (i < 32768 + 16384) {
        int j = i - 32768;
        int n = j >> 7, k = j & 127;
        float v = (n < OUTC) ? Wmu[k * OUTC + n] : Wls[k * OUTC + (n - OUTC)];
        wct[j] = f2bf(v);
    } else if (i < 32768 + 16384 + 128) {
        int c = i - (32768 + 16384);
        bcat[c] = (c < OUTC) ? bmu[c] : bls[c - OUTC];
    }
}

// ---------------- MFMA GEMM1: out_bf16[M,128] = bf16(x[M,256]) @ wt^T ----------------
// LDS-staged via global_load_lds DMA; 16B-chunk XOR swizzle on global source +
// ds_read slot (LDS dest linear, as HW requires). See round-3 notes.
__global__ __launch_bounds__(256, 2) void k_mgemm1(const float* __restrict__ x,
                                                   const short* __restrict__ wt,
                                                   short* __restrict__ out) {
    __shared__ __align__(16) float xs[64 * 256];   // 64KB, chunk-swizzled rows
    int wave = threadIdx.x >> 6;
    int lane = threadIdx.x & 63;
    int m = lane & 15, quad = lane >> 4;
    int rbase = blockIdx.x * 64;

#pragma unroll
    for (int i = 0; i < 16; i++) {
        int r = wave * 16 + i;                       // wave-uniform
        int grow = rbase + r;
        if (grow >= NN) grow = NN - 1;               // clamp; stores guarded
        const float* gsrc = x + (size_t)grow * INCH + ((lane ^ (r & 7)) << 2);
        float* ldst = xs + r * INCH;                 // lane l -> +l*16B
        async_copy16(gsrc, ldst);
    }

    // B prefetch (L2-resident 64KB wt) rides under the same vmcnt as the DMA.
    short8 bfr[2][8];
#pragma unroll
    for (int ct = 0; ct < 2; ct++)
#pragma unroll
        for (int k0 = 0; k0 < 8; k0++)
            bfr[ct][k0] = *(const short8*)(wt + (size_t)(wave * 32 + ct * 16 + m) * INCH
                                              + k0 * 32 + quad * 8);

    asm volatile("s_waitcnt vmcnt(0)" ::: "memory");
    __syncthreads();

    floatx4 acc[4][2];
#pragma unroll
    for (int rt = 0; rt < 4; rt++) { acc[rt][0] = (floatx4)(0.f); acc[rt][1] = (floatx4)(0.f); }

#pragma unroll
    for (int k0 = 0; k0 < 8; k0++) {
        int cbase = k0 * 8 + (quad << 1);            // 16B-chunk index of lane's 8 floats
#pragma unroll
        for (int rt = 0; rt < 4; rt++) {
            int r = rt * 16 + m;
            int e = m & 7;                           // (rt*16+m)&7 == m&7
            const float* p0 = xs + r * INCH + (((cbase) ^ e) << 2);
            const float* p1 = xs + r * INCH + (((cbase + 1) ^ e) << 2);
            float4 f0 = *(const float4*)p0;
            float4 f1 = *(const float4*)p1;
            union { short8 s; unsigned u[4]; } a;
            a.u[0] = pk2bf(f0.x, f0.y); a.u[1] = pk2bf(f0.z, f0.w);
            a.u[2] = pk2bf(f1.x, f1.y); a.u[3] = pk2bf(f1.z, f1.w);
            acc[rt][0] = __builtin_amdgcn_mfma_f32_16x16x32_bf16(a.s, bfr[0][k0], acc[rt][0], 0, 0, 0);
            acc[rt][1] = __builtin_amdgcn_mfma_f32_16x16x32_bf16(a.s, bfr[1][k0], acc[rt][1], 0, 0, 0);
        }
    }

#pragma unroll
    for (int rt = 0; rt < 4; rt++) {
        int rs = rbase + rt * 16 + quad * 4;
#pragma unroll
        for (int ct = 0; ct < 2; ct++) {
            int c = wave * 32 + ct * 16 + m;
#pragma unroll
            for (int r = 0; r < 4; r++) {
                int rr = rs + r;
                if (rr < NN) out[(size_t)rr * HIDC + c] = f2bf(acc[rt][ct][r]);
            }
        }
    }
}

// ---------------- MFMA GEMM2: [mu|logstd] = agg_bf16[M,128] @ wct^T + bcat ----------------
// All 8 A-operand loads per lane prefetched upfront, pinned by sched_barrier.
__global__ __launch_bounds__(256, 1) void k_mgemm2(const short* __restrict__ agg,
                                                   const short* __restrict__ wct,
                                                   const float* __restrict__ bcat,
                                                   float* __restrict__ out) {
    int wave = threadIdx.x >> 6;
    int lane = threadIdx.x & 63;
    int rhalf = wave & 1, chalf = wave >> 1;
    int m = lane & 15, quad = lane >> 4;
    int rbase = blockIdx.x * 64 + rhalf * 32;
    int r0c = min(rbase + m, NN - 1);
    int r1c = min(rbase + 16 + m, NN - 1);
    const short* ar0 = agg + (size_t)r0c * HIDC + quad * 8;
    const short* ar1 = agg + (size_t)r1c * HIDC + quad * 8;

    // prefetch all A fragments (8 x 16B per lane)
    short8 pa0[4], pa1[4];
#pragma unroll
    for (int c = 0; c < 4; c++) {
        pa0[c] = *(const short8*)(ar0 + c * 32);
        pa1[c] = *(const short8*)(ar1 + c * 32);
    }
    __builtin_amdgcn_sched_barrier(0);

    const short* wbase = wct + quad * 8 + (size_t)m * HIDC + (size_t)(chalf * 4) * 16 * HIDC;
    floatx4 acc0[4], acc1[4];
#pragma unroll
    for (int i = 0; i < 4; i++) { acc0[i] = (floatx4)(0.f); acc1[i] = (floatx4)(0.f); }
#pragma unroll
    for (int k = 0; k < 4; k++) {
        const short* wq = wbase + k * 32;
#pragma unroll
        for (int nt = 0; nt < 4; nt++) {
            short8 b = *(const short8*)(wq + (size_t)nt * 16 * HIDC);
            acc0[nt] = __builtin_amdgcn_mfma_f32_16x16x32_bf16(pa0[k], b, acc0[nt], 0, 0, 0);
            acc1[nt] = __builtin_amdgcn_mfma_f32_16x16x32_bf16(pa1[k], b, acc1[nt], 0, 0, 0);
        }
    }
    int rs0 = rbase + quad * 4;
    int rs1 = rbase + 16 + quad * 4;
#pragma unroll
    for (int nt = 0; nt < 4; nt++) {
        int c = (chalf * 4 + nt) * 16 + m;
        float bv = bcat[c];
        float* obase = (c < OUTC) ? (out + c) : (out + (size_t)NN * OUTC + (c - OUTC));
#pragma unroll
        for (int r = 0; r < 4; r++) {
            int rr = rs0 + r;
            if (rr < NN) obase[(size_t)rr * OUTC] = acc0[nt][r] + bv;
            int rr2 = rs1 + r;
            if (rr2 < NN) obase[(size_t)rr2 * OUTC] = acc1[nt][r] + bv;
        }
    }
}

// ---------------- gather aggregation: ONE WAVE per dst row, 2 bf16 ch per lane ----------------
// Round-4 lesson: 16-lane groups pay ~22 wave-instr/edge + ~45% divergence waste
// (4 independent deg-loops per wave run to the max). One dst per wave: zero
// divergence, ~10 instr/edge (1 dword load = full 256B row per instruction,
// 2 unpack + 2 fma per lane). Per-channel accumulation order unchanged
// (ascending CSR order) -> bit-identical numerics. Row end comes from the
// post-fill cursor (= row_off + deg), dropping the deg load.
template <bool RELU>
__global__ __launch_bounds__(256) void k_gather(const short* __restrict__ feat,
                                                const int* __restrict__ esrc,
                                                const int* __restrict__ row_off,
                                                const int* __restrict__ rend,
                                                const float* __restrict__ dinv,
                                                const float* __restrict__ bias,
                                                short* __restrict__ out) {
    int d = (blockIdx.x * 256 + threadIdx.x) >> 6;   // one wave per dst node
    int l = threadIdx.x & 63;                        // lane -> channels {2l, 2l+1}
    if (d >= NN) return;
    const unsigned* fp = (const unsigned*)feat;      // 1 dword = 2 bf16 channels
    float dd = dinv[d];
    float sw = dd * dd;
    unsigned sv = fp[(size_t)d * 64 + l];
    float a0 = __uint_as_float(sv << 16) * sw;
    float a1 = __uint_as_float(sv & 0xffff0000u) * sw;
    int off = row_off[d];
    int cnt = rend[d] - off;
    for (int base = 0; base < cnt; base += 64) {
        int mm = min(64, cnt - base);
        int sj = (l < mm) ? esrc[off + base + l] : 0;
        float dj = (l < mm) ? dinv[sj] : 0.f;
        int j = 0;
        for (; j + 4 <= mm; j += 4) {
            int s0 = __shfl(sj, j + 0); float n0 = __shfl(dj, j + 0) * dd;
            int s1 = __shfl(sj, j + 1); float n1 = __shfl(dj, j + 1) * dd;
            int s2 = __shfl(sj, j + 2); float n2 = __shfl(dj, j + 2) * dd;
            int s3 = __shfl(sj, j + 3); float n3 = __shfl(dj, j + 3) * dd;
            unsigned v0 = fp[(size_t)s0 * 64 + l];
            unsigned v1 = fp[(size_t)s1 * 64 + l];
            unsigned v2 = fp[(size_t)s2 * 64 + l];
            unsigned v3 = fp[(size_t)s3 * 64 + l];
            a0 = fmaf(__uint_as_float(v0 << 16), n0, a0);
            a1 = fmaf(__uint_as_float(v0 & 0xffff0000u), n0, a1);
            a0 = fmaf(__uint_as_float(v1 << 16), n1, a0);
            a1 = fmaf(__uint_as_float(v1 & 0xffff0000u), n1, a1);
            a0 = fmaf(__uint_as_float(v2 << 16), n2, a0);
            a1 = fmaf(__uint_as_float(v2 & 0xffff0000u), n2, a1);
            a0 = fmaf(__uint_as_float(v3 << 16), n3, a0);
            a1 = fmaf(__uint_as_float(v3 & 0xffff0000u), n3, a1);
        }
        for (; j < mm; j++) {
            int s0 = __shfl(sj, j); float n0 = __shfl(dj, j) * dd;
            unsigned v0 = fp[(size_t)s0 * 64 + l];
            a0 = fmaf(__uint_as_float(v0 << 16), n0, a0);
            a1 = fmaf(__uint_as_float(v0 & 0xffff0000u), n0, a1);
        }
    }
    if (RELU) {
        float2 b = ((const float2*)bias)[l];
        a0 = fmaxf(a0 + b.x, 0.f);
        a1 = fmaxf(a1 + b.y, 0.f);
    }
    ((unsigned*)out)[(size_t)d * 64 + l] = pk2bf(a0, a1);
}

extern "C" void kernel_launch(void* const* d_in, const int* in_sizes, int n_in,
                              void* d_out, int out_size, void* d_ws, size_t ws_size,
                              hipStream_t stream) {
    const float* x   = (const float*)d_in[0];
    const float* W1  = (const float*)d_in[1];
    const float* b1  = (const float*)d_in[2];
    const float* Wmu = (const float*)d_in[3];
    const float* bmu = (const float*)d_in[4];
    const float* Wls = (const float*)d_in[5];
    const float* bls = (const float*)d_in[6];
    const int*   ei  = (const int*)d_in[7];
    const int* srcp = ei;        // edge_index[0]
    const int* dstp = ei + EE;   // edge_index[1]

    float* out = (float*)d_out;

    // workspace layout
    char* wsb = (char*)d_ws;
    short* bufA    = (short*)wsb;                        // N*128 bf16: XW1, then agg2 (25.6 MB)
    short* bufH    = bufA + (size_t)NN * HIDC;           // N*128 bf16: h (25.6 MB)
    int*   deg     = (int*)(bufH + (size_t)NN * HIDC);
    int*   row_off = deg + NN;
    int*   cursor  = row_off + NN;
    float* dinv    = (float*)(cursor + NN);
    int*   esrc    = (int*)(dinv + NN);                  // E ints
    int*   partials = esrc + EE;                         // NCHUNK ints
    short* wt      = (short*)(partials + NCHUNK + 1);    // 128*256 bf16
    short* wct     = wt + 128 * 256;                     // 128*128 bf16
    float* bcat    = (float*)(wct + 128 * 128);          // 128 f32

    const int nb_n = (NN + 255) / 256;
    const int nb_e = (EE + 255) / 256;
    const int nb_g = (NN * 64) / 256;          // 25000: one wave per dst
    const int nb_m = (NN + 63) / 64;           // 1563 MFMA blocks

    // CSR build + norm + weight prep
    k_deg_zero<<<nb_n, 256, 0, stream>>>(deg);
    k_deg_count<<<nb_e, 256, 0, stream>>>(dstp, deg);
    k_scan1<<<NCHUNK, 256, 0, stream>>>(deg, partials);
    k_scan2<<<1, 512, 0, stream>>>(partials);
    k_scan3<<<NCHUNK, 256, 0, stream>>>(deg, partials, row_off, cursor, dinv);
    k_fill<<<nb_e, 256, 0, stream>>>(srcp, dstp, cursor, esrc);
    k_prep<<<193, 256, 0, stream>>>(W1, Wmu, bmu, Wls, bls, wt, wct, bcat);

    // layer 1: XW1 -> bufA (bf16, MFMA); h = relu(agg(bufA) + b1) -> bufH (bf16)
    k_mgemm1<<<nb_m, 256, 0, stream>>>(x, wt, bufA);
    k_gather<true><<<nb_g, 256, 0, stream>>>(bufA, esrc, row_off, cursor, dinv, b1, bufH);

    // layer 2/3: agg2 = agg(h) -> bufA (bf16); [mu|logstd] = bufA @ wct^T + bcat -> d_out
    k_gather<false><<<nb_g, 256, 0, stream>>>(bufH, esrc, row_off, cursor, dinv, nullptr, bufA);
    k_mgemm2<<<nb_m, 256, 0, stream>>>(bufA, wct, bcat, out);
}

// Round 6
// 347.728 us; speedup vs baseline: 1.0611x; 1.0611x over previous
//
#include <hip/hip_runtime.h>
#include <math.h>

#define NN 100000
#define EE 640000
#define INCH 256
#define HIDC 128
#define OUTC 64
#define NCHUNK ((NN + 255) / 256)   // 391 scan chunks

typedef __attribute__((ext_vector_type(8))) short short8;
typedef __attribute__((ext_vector_type(8))) unsigned short ushort8;
typedef __attribute__((ext_vector_type(4))) float floatx4;

__device__ __forceinline__ short f2bf(float f) {
    unsigned u = __float_as_uint(f);
    u += 0x7fff + ((u >> 16) & 1);   // round-to-nearest-even
    return (short)(u >> 16);
}

__device__ __forceinline__ float bf2f(unsigned short u) {
    return __uint_as_float(((unsigned)u) << 16);
}

// packed f32x2 -> bf16x2 (RNE), one VALU op instead of ~8
__device__ __forceinline__ unsigned pk2bf(float lo, float hi) {
    unsigned r;
    asm("v_cvt_pk_bf16_f32 %0, %1, %2" : "=v"(r) : "v"(lo), "v"(hi));
    return r;
}

// async global->LDS DMA, 16B per lane; LDS dest = wave-uniform base + lane*16
__device__ __forceinline__ void async_copy16(const void* g, void* l) {
    __builtin_amdgcn_global_load_lds(
        (const __attribute__((address_space(1))) unsigned int*)g,
        (__attribute__((address_space(3))) unsigned int*)l,
        16, 0, 0);
}

// ---------------- degree ----------------
__global__ void k_deg_zero(int* __restrict__ deg) {
    int i = blockIdx.x * 256 + threadIdx.x;
    if (i < NN) deg[i] = 0;
}

__global__ void k_deg_count(const int* __restrict__ dstp, int* __restrict__ deg) {
    int e = blockIdx.x * 256 + threadIdx.x;
    if (e < EE) atomicAdd(&deg[dstp[e]], 1);
}

// ---------------- scan (exclusive prefix over deg) ----------------
__global__ __launch_bounds__(256) void k_scan1(const int* __restrict__ deg,
                                               int* __restrict__ partials) {
    int i = blockIdx.x * 256 + threadIdx.x;
    int v = (i < NN) ? deg[i] : 0;
    for (int o = 32; o; o >>= 1) v += __shfl_down(v, o, 64);
    __shared__ int sm[4];
    if ((threadIdx.x & 63) == 0) sm[threadIdx.x >> 6] = v;
    __syncthreads();
    if (threadIdx.x == 0) partials[blockIdx.x] = sm[0] + sm[1] + sm[2] + sm[3];
}

__global__ __launch_bounds__(512) void k_scan2(int* __restrict__ partials) {
    __shared__ int sm[512];
    int t = threadIdx.x;
    int v = (t < NCHUNK) ? partials[t] : 0;
    sm[t] = v;
    __syncthreads();
    for (int o = 1; o < 512; o <<= 1) {
        int add = (t >= o) ? sm[t - o] : 0;
        __syncthreads();
        sm[t] += add;
        __syncthreads();
    }
    if (t < NCHUNK) partials[t] = sm[t] - v;  // exclusive
}

__global__ __launch_bounds__(256) void k_scan3(const int* __restrict__ deg,
                                               const int* __restrict__ partials,
                                               int* __restrict__ row_off,
                                               int* __restrict__ cursor,
                                               float* __restrict__ dinv) {
    int t = threadIdx.x;
    int i = blockIdx.x * 256 + t;
    int v = (i < NN) ? deg[i] : 0;
    __shared__ int sm[256];
    sm[t] = v;
    __syncthreads();
    for (int o = 1; o < 256; o <<= 1) {
        int add = (t >= o) ? sm[t - o] : 0;
        __syncthreads();
        sm[t] += add;
        __syncthreads();
    }
    if (i < NN) {
        int excl = partials[blockIdx.x] + sm[t] - v;
        row_off[i] = excl;
        cursor[i] = excl;
        dinv[i] = rsqrtf((float)(v + 1));  // +1 self-loop
    }
}

// ---------------- CSR fill ----------------
__global__ void k_fill(const int* __restrict__ srcp, const int* __restrict__ dstp,
                       int* __restrict__ cursor, int* __restrict__ esrc) {
    int e = blockIdx.x * 256 + threadIdx.x;
    if (e < EE) {
        int d = dstp[e];
        int pos = atomicAdd(&cursor[d], 1);
        esrc[pos] = srcp[e];
    }
}

// ---------------- weight prep: transpose + bf16 ----------------
__global__ void k_prep(const float* __restrict__ W1,
                       const float* __restrict__ Wmu, const float* __restrict__ bmu,
                       const float* __restrict__ Wls, const float* __restrict__ bls,
                       short* __restrict__ wt, short* __restrict__ wct,
                       float* __restrict__ bcat) {
    int i = blockIdx.x * 256 + threadIdx.x;
    if (i < 32768) {
        int n = i >> 8, k = i & 255;
        wt[i] = f2bf(W1[k * HIDC + n]);
    } else if (i < 32768 + 16384) {
        int j = i - 32768;
        int n = j >> 7, k = j & 127;
        float v = (n < OUTC) ? Wmu[k * OUTC + n] : Wls[k * OUTC + (n - OUTC)];
        wct[j] = f2bf(v);
    } else if (i < 32768 + 16384 + 128) {
        int c = i - (32768 + 16384);
        bcat[c] = (c < OUTC) ? bmu[c] : bls[c - OUTC];
    }
}

// ---------------- MFMA GEMM1: out_bf16[M,128] = bf16(x[M,256]) @ wt^T ----------------
// 2-phase K-split pipeline (T3/T4-lite): tile = 64 rows, two K-halves of 128
// cols (2 x 32KB LDS). Issue half0 DMA -> B loads -> half1 DMA up front; then
// counted s_waitcnt vmcnt(8) (= half0 + B complete, half1 STAYS IN FLIGHT
// across the raw s_barrier) -> compute half0 -> vmcnt(0) + barrier -> compute
// half1. Half1's DMA hides under half0's compute; no full drain at barrier 1.
// XOR-chunk swizzle keyed on LOCAL row (r&7), same key on DMA source and
// ds_read slot (LDS dest linear, as HW requires).
__global__ __launch_bounds__(256, 2) void k_mgemm1(const float* __restrict__ x,
                                                   const short* __restrict__ wt,
                                                   short* __restrict__ out) {
    __shared__ __align__(16) float xs[2][64 * 128];   // 2 x 32KB K-halves
    int wave = threadIdx.x >> 6;
    int lane = threadIdx.x & 63;
    int m = lane & 15, quad = lane >> 4;
    int rbase = blockIdx.x * 64;

    // ---- issue phase: half0 DMA (8), B loads (16), half1 DMA (8) ----
    // 2 rows per DMA instr: lanes 0-31 -> row r, lanes 32-63 -> row r+1 (512B each).
#pragma unroll
    for (int i = 0; i < 8; i++) {
        int r = wave * 16 + 2 * i + (lane >> 5);          // local row (per-lane)
        int grow = rbase + r; if (grow >= NN) grow = NN - 1;
        int chunk = (lane & 31) ^ (r & 7);                // key = LOCAL row
        const float* gsrc = x + (size_t)grow * INCH + chunk * 4;
        float* ldst = xs[0] + (wave * 16 + 2 * i) * 128;  // wave-uniform base
        async_copy16(gsrc, ldst);
    }

    short8 bfr[2][8];
#pragma unroll
    for (int ct = 0; ct < 2; ct++)
#pragma unroll
        for (int kg = 0; kg < 8; kg++)
            bfr[ct][kg] = *(const short8*)(wt + (size_t)(wave * 32 + ct * 16 + m) * INCH
                                              + kg * 32 + quad * 8);

#pragma unroll
    for (int i = 0; i < 8; i++) {
        int r = wave * 16 + 2 * i + (lane >> 5);
        int grow = rbase + r; if (grow >= NN) grow = NN - 1;
        int chunk = (lane & 31) ^ (r & 7);
        const float* gsrc = x + (size_t)grow * INCH + 128 + chunk * 4;
        float* ldst = xs[1] + (wave * 16 + 2 * i) * 128;
        async_copy16(gsrc, ldst);
    }

    floatx4 acc[4][2];
#pragma unroll
    for (int rt = 0; rt < 4; rt++) { acc[rt][0] = (floatx4)(0.f); acc[rt][1] = (floatx4)(0.f); }

#define COMPUTE_HALF(h)                                                                  \
    _Pragma("unroll")                                                                    \
    for (int k0 = 0; k0 < 4; k0++) {                                                     \
        int cb = k0 * 8 + (quad << 1);              /* 16B-chunk index, 0..31 */         \
        _Pragma("unroll")                                                                \
        for (int rt = 0; rt < 4; rt++) {                                                 \
            int r = rt * 16 + m;                                                         \
            int key = m & 7;                        /* (rt*16+m)&7 == m&7 */             \
            const float* p0 = xs[h] + r * 128 + (((cb) ^ key) << 2);                     \
            const float* p1 = xs[h] + r * 128 + (((cb + 1) ^ key) << 2);                 \
            float4 f0 = *(const float4*)p0;                                              \
            float4 f1 = *(const float4*)p1;                                              \
            union { short8 s; unsigned u[4]; } a;                                        \
            a.u[0] = pk2bf(f0.x, f0.y); a.u[1] = pk2bf(f0.z, f0.w);                      \
            a.u[2] = pk2bf(f1.x, f1.y); a.u[3] = pk2bf(f1.z, f1.w);                      \
            acc[rt][0] = __builtin_amdgcn_mfma_f32_16x16x32_bf16(a.s, bfr[0][(h)*4+k0],  \
                                                                 acc[rt][0], 0, 0, 0);   \
            acc[rt][1] = __builtin_amdgcn_mfma_f32_16x16x32_bf16(a.s, bfr[1][(h)*4+k0],  \
                                                                 acc[rt][1], 0, 0, 0);   \
        }                                                                                \
    }

    asm volatile("s_waitcnt vmcnt(8)" ::: "memory");   // half0 + B done; half1 in flight
    __builtin_amdgcn_sched_barrier(0);
    __builtin_amdgcn_s_barrier();
    COMPUTE_HALF(0)
    asm volatile("s_waitcnt vmcnt(0)" ::: "memory");   // half1 done
    __builtin_amdgcn_sched_barrier(0);
    __builtin_amdgcn_s_barrier();
    COMPUTE_HALF(1)
#undef COMPUTE_HALF

#pragma unroll
    for (int rt = 0; rt < 4; rt++) {
        int rs = rbase + rt * 16 + quad * 4;
#pragma unroll
        for (int ct = 0; ct < 2; ct++) {
            int c = wave * 32 + ct * 16 + m;
#pragma unroll
            for (int r = 0; r < 4; r++) {
                int rr = rs + r;
                if (rr < NN) out[(size_t)rr * HIDC + c] = f2bf(acc[rt][ct][r]);
            }
        }
    }
}

// ---------------- MFMA GEMM2: [mu|logstd] = agg_bf16[M,128] @ wct^T + bcat ----------------
// All 8 A-operand loads per lane prefetched upfront, pinned by sched_barrier.
__global__ __launch_bounds__(256, 1) void k_mgemm2(const short* __restrict__ agg,
                                                   const short* __restrict__ wct,
                                                   const float* __restrict__ bcat,
                                                   float* __restrict__ out) {
    int wave = threadIdx.x >> 6;
    int lane = threadIdx.x & 63;
    int rhalf = wave & 1, chalf = wave >> 1;
    int m = lane & 15, quad = lane >> 4;
    int rbase = blockIdx.x * 64 + rhalf * 32;
    int r0c = min(rbase + m, NN - 1);
    int r1c = min(rbase + 16 + m, NN - 1);
    const short* ar0 = agg + (size_t)r0c * HIDC + quad * 8;
    const short* ar1 = agg + (size_t)r1c * HIDC + quad * 8;

    // prefetch all A fragments (8 x 16B per lane)
    short8 pa0[4], pa1[4];
#pragma unroll
    for (int c = 0; c < 4; c++) {
        pa0[c] = *(const short8*)(ar0 + c * 32);
        pa1[c] = *(const short8*)(ar1 + c * 32);
    }
    __builtin_amdgcn_sched_barrier(0);

    const short* wbase = wct + quad * 8 + (size_t)m * HIDC + (size_t)(chalf * 4) * 16 * HIDC;
    floatx4 acc0[4], acc1[4];
#pragma unroll
    for (int i = 0; i < 4; i++) { acc0[i] = (floatx4)(0.f); acc1[i] = (floatx4)(0.f); }
#pragma unroll
    for (int k = 0; k < 4; k++) {
        const short* wq = wbase + k * 32;
#pragma unroll
        for (int nt = 0; nt < 4; nt++) {
            short8 b = *(const short8*)(wq + (size_t)nt * 16 * HIDC);
            acc0[nt] = __builtin_amdgcn_mfma_f32_16x16x32_bf16(pa0[k], b, acc0[nt], 0, 0, 0);
            acc1[nt] = __builtin_amdgcn_mfma_f32_16x16x32_bf16(pa1[k], b, acc1[nt], 0, 0, 0);
        }
    }
    int rs0 = rbase + quad * 4;
    int rs1 = rbase + 16 + quad * 4;
#pragma unroll
    for (int nt = 0; nt < 4; nt++) {
        int c = (chalf * 4 + nt) * 16 + m;
        float bv = bcat[c];
        float* obase = (c < OUTC) ? (out + c) : (out + (size_t)NN * OUTC + (c - OUTC));
#pragma unroll
        for (int r = 0; r < 4; r++) {
            int rr = rs0 + r;
            if (rr < NN) obase[(size_t)rr * OUTC] = acc0[nt][r] + bv;
            int rr2 = rs1 + r;
            if (rr2 < NN) obase[(size_t)rr2 * OUTC] = acc1[nt][r] + bv;
        }
    }
}

// ---------------- gather aggregation: 16 lanes per dst row, bf16 in/out, 4x unrolled ----------------
// (r3 known-good form. r5 lesson: one-wave-per-dst removed divergence but lost
// the 4 independent row-load streams per wave -> latency-bound regression.
// The 16-lane layout's MLP matters more than its divergence tax.)
template <bool RELU>
__global__ __launch_bounds__(256) void k_gather(const short* __restrict__ feat,
                                                const int* __restrict__ esrc,
                                                const int* __restrict__ row_off,
                                                const int* __restrict__ deg,
                                                const float* __restrict__ dinv,
                                                const float* __restrict__ bias,
                                                short* __restrict__ out) {
    int gid = blockIdx.x * 256 + threadIdx.x;
    int d = gid >> 4;          // one 16-lane group per dst node
    int l = threadIdx.x & 15;  // 16 lanes x 8 ch (ushort8) = 128 ch
    if (d >= NN) return;
    const ushort8* fp = (const ushort8*)feat;
    float dd = dinv[d];
    float sw = dd * dd;
    ushort8 sv = fp[(size_t)d * 16 + l];
    float acc[8];
#pragma unroll
    for (int i = 0; i < 8; i++) acc[i] = bf2f(sv[i]) * sw;
    int off = row_off[d];
    int cnt = deg[d];
    for (int base = 0; base < cnt; base += 16) {
        int mm = min(16, cnt - base);
        int sj = (l < mm) ? esrc[off + base + l] : 0;
        float dj = (l < mm) ? dinv[sj] : 0.f;
        int j = 0;
        for (; j + 4 <= mm; j += 4) {
            int s0 = __shfl(sj, j + 0, 16);
            int s1 = __shfl(sj, j + 1, 16);
            int s2 = __shfl(sj, j + 2, 16);
            int s3 = __shfl(sj, j + 3, 16);
            float n0 = __shfl(dj, j + 0, 16) * dd;
            float n1 = __shfl(dj, j + 1, 16) * dd;
            float n2 = __shfl(dj, j + 2, 16) * dd;
            float n3 = __shfl(dj, j + 3, 16) * dd;
            ushort8 v0 = fp[(size_t)s0 * 16 + l];
            ushort8 v1 = fp[(size_t)s1 * 16 + l];
            ushort8 v2 = fp[(size_t)s2 * 16 + l];
            ushort8 v3 = fp[(size_t)s3 * 16 + l];
#pragma unroll
            for (int i = 0; i < 8; i++) acc[i] = fmaf(bf2f(v0[i]), n0, acc[i]);
#pragma unroll
            for (int i = 0; i < 8; i++) acc[i] = fmaf(bf2f(v1[i]), n1, acc[i]);
#pragma unroll
            for (int i = 0; i < 8; i++) acc[i] = fmaf(bf2f(v2[i]), n2, acc[i]);
#pragma unroll
            for (int i = 0; i < 8; i++) acc[i] = fmaf(bf2f(v3[i]), n3, acc[i]);
        }
        if (j + 2 <= mm) {
            int s0 = __shfl(sj, j + 0, 16);
            int s1 = __shfl(sj, j + 1, 16);
            float n0 = __shfl(dj, j + 0, 16) * dd;
            float n1 = __shfl(dj, j + 1, 16) * dd;
            ushort8 v0 = fp[(size_t)s0 * 16 + l];
            ushort8 v1 = fp[(size_t)s1 * 16 + l];
#pragma unroll
            for (int i = 0; i < 8; i++) acc[i] = fmaf(bf2f(v0[i]), n0, acc[i]);
#pragma unroll
            for (int i = 0; i < 8; i++) acc[i] = fmaf(bf2f(v1[i]), n1, acc[i]);
            j += 2;
        }
        if (j < mm) {
            int s0 = __shfl(sj, j, 16);
            float n0 = __shfl(dj, j, 16) * dd;
            ushort8 v0 = fp[(size_t)s0 * 16 + l];
#pragma unroll
            for (int i = 0; i < 8; i++) acc[i] = fmaf(bf2f(v0[i]), n0, acc[i]);
        }
    }
    if (RELU) {
        float4 b0 = *(const float4*)(bias + l * 8);
        float4 b1 = *(const float4*)(bias + l * 8 + 4);
        acc[0] = fmaxf(acc[0] + b0.x, 0.f);
        acc[1] = fmaxf(acc[1] + b0.y, 0.f);
        acc[2] = fmaxf(acc[2] + b0.z, 0.f);
        acc[3] = fmaxf(acc[3] + b0.w, 0.f);
        acc[4] = fmaxf(acc[4] + b1.x, 0.f);
        acc[5] = fmaxf(acc[5] + b1.y, 0.f);
        acc[6] = fmaxf(acc[6] + b1.z, 0.f);
        acc[7] = fmaxf(acc[7] + b1.w, 0.f);
    }
    ushort8 o;
#pragma unroll
    for (int i = 0; i < 8; i++) o[i] = (unsigned short)f2bf(acc[i]);
    ((ushort8*)out)[(size_t)d * 16 + l] = o;
}

extern "C" void kernel_launch(void* const* d_in, const int* in_sizes, int n_in,
                              void* d_out, int out_size, void* d_ws, size_t ws_size,
                              hipStream_t stream) {
    const float* x   = (const float*)d_in[0];
    const float* W1  = (const float*)d_in[1];
    const float* b1  = (const float*)d_in[2];
    const float* Wmu = (const float*)d_in[3];
    const float* bmu = (const float*)d_in[4];
    const float* Wls = (const float*)d_in[5];
    const float* bls = (const float*)d_in[6];
    const int*   ei  = (const int*)d_in[7];
    const int* srcp = ei;        // edge_index[0]
    const int* dstp = ei + EE;   // edge_index[1]

    float* out = (float*)d_out;

    // workspace layout
    char* wsb = (char*)d_ws;
    short* bufA    = (short*)wsb;                        // N*128 bf16: XW1, then agg2 (25.6 MB)
    short* bufH    = bufA + (size_t)NN * HIDC;           // N*128 bf16: h (25.6 MB)
    int*   deg     = (int*)(bufH + (size_t)NN * HIDC);
    int*   row_off = deg + NN;
    int*   cursor  = row_off + NN;
    float* dinv    = (float*)(cursor + NN);
    int*   esrc    = (int*)(dinv + NN);                  // E ints
    int*   partials = esrc + EE;                         // NCHUNK ints
    short* wt      = (short*)(partials + NCHUNK + 1);    // 128*256 bf16
    short* wct     = wt + 128 * 256;                     // 128*128 bf16
    float* bcat    = (float*)(wct + 128 * 128);          // 128 f32

    const int nb_n = (NN + 255) / 256;
    const int nb_e = (EE + 255) / 256;
    const int nb_g = (NN * 16) / 256;          // 6250 exact
    const int nb_m = (NN + 63) / 64;           // 1563 MFMA blocks

    // CSR build + norm + weight prep
    k_deg_zero<<<nb_n, 256, 0, stream>>>(deg);
    k_deg_count<<<nb_e, 256, 0, stream>>>(dstp, deg);
    k_scan1<<<NCHUNK, 256, 0, stream>>>(deg, partials);
    k_scan2<<<1, 512, 0, stream>>>(partials);
    k_scan3<<<NCHUNK, 256, 0, stream>>>(deg, partials, row_off, cursor, dinv);
    k_fill<<<nb_e, 256, 0, stream>>>(srcp, dstp, cursor, esrc);
    k_prep<<<193, 256, 0, stream>>>(W1, Wmu, bmu, Wls, bls, wt, wct, bcat);

    // layer 1: XW1 -> bufA (bf16, MFMA); h = relu(agg(bufA) + b1) -> bufH (bf16)
    k_mgemm1<<<nb_m, 256, 0, stream>>>(x, wt, bufA);
    k_gather<true><<<nb_g, 256, 0, stream>>>(bufA, esrc, row_off, deg, dinv, b1, bufH);

    // layer 2/3: agg2 = agg(h) -> bufA (bf16); [mu|logstd] = bufA @ wct^T + bcat -> d_out
    k_gather<false><<<nb_g, 256, 0, stream>>>(bufH, esrc, row_off, deg, dinv, nullptr, bufA);
    k_mgemm2<<<nb_m, 256, 0, stream>>>(bufA, wct, bcat, out);
}